// Round 1
// baseline (375.451 us; speedup 1.0000x reference)
//
#include <hip/hip_runtime.h>

// SpectralConv2d: B=16, C_in=C_out=64, H=W=256, k=16.
// Only modes (rows 0..15 & 240..255) x (cols 0..15) survive -> direct sparse DFTs.
//
// Pipeline (all fp32):
//  k_twiddle : cos/sin table (256 entries) into ws
//  k_repack  : R'[m][wm][c][o] = (Wre + i Wim) * (wm==0?1:2)/65536  (norm folded)
//  k_fwd     : per (b,c): x-DFT (16 cols) then y-DFT (32 row-modes) -> U[b][c][m][wm]
//  k_cgemm   : per (m,wm): V[b][o] = sum_c U[b][c] * R'[c][o]   (complex)
//  k_inv     : per (b,o): inverse y-DFT -> T[y][wm]; out[y][x] = sum_wm TR*cos - TI*sin

#define B_    16
#define CIN   64
#define COUT  64
#define H_    256
#define W_    256
#define NM_   32      // row modes: m<16 -> f=m ; m>=16 -> f=m-32
#define KW_   16

// workspace float offsets
#define OFF_CT 0
#define OFF_ST 256
#define OFF_RP 512
#define RP_SZ  (NM_*KW_*CIN*COUT*2)            // 4,194,304 floats
#define OFF_U  (OFF_RP + RP_SZ)                // 4,194,816
#define U_SZ   (B_*CIN*NM_*KW_*2)              // 1,048,576
#define OFF_V  (OFF_U + U_SZ)                  // 5,243,392
#define V_SZ   (B_*COUT*NM_*KW_*2)             // 1,048,576
// total ws need: (OFF_V + V_SZ)*4 bytes ~= 25.2 MB

__global__ void k_twiddle(float* __restrict__ ws) {
    int t = threadIdx.x;
    double a = 2.0 * 3.14159265358979323846 * (double)t / 256.0;
    ws[OFF_CT + t] = (float)cos(a);
    ws[OFF_ST + t] = (float)sin(a);
}

__global__ __launch_bounds__(256) void k_repack(const float* __restrict__ wpr,
                                                const float* __restrict__ wpi,
                                                const float* __restrict__ wnr,
                                                const float* __restrict__ wni,
                                                float* __restrict__ ws) {
    int mw = blockIdx.x;              // 0..511  (m*16 + wm)
    int m  = mw >> 4, wm = mw & 15;
    const float* wr; const float* wi; int i;
    if (m < 16) { wr = wpr; wi = wpi; i = m; }
    else        { wr = wnr; wi = wni; i = m - 16; }
    float norm = (wm == 0 ? 1.0f : 2.0f) / 65536.0f;
    float* rp = ws + OFF_RP + (size_t)mw * (CIN * COUT * 2);
    int off = i * 16 + wm;
    #pragma unroll
    for (int k = 0; k < 16; ++k) {
        int co = threadIdx.x + 256 * k;       // c*64 + o
        float re = wr[(size_t)co * 256 + off] * norm;
        float im = wi[(size_t)co * 256 + off] * norm;
        rp[(size_t)co * 2]     = re;
        rp[(size_t)co * 2 + 1] = im;
    }
}

// forward: one block per (b,c). Stage 1: x-DFT via phase recurrence.
// Stage 2: y-DFT onto 32 modes.
__global__ __launch_bounds__(256) void k_fwd(const float* __restrict__ u,
                                             const float* __restrict__ ws,
                                             float* __restrict__ U) {
    __shared__ float ut[32][258];          // chunk of 32 rows, padded
    __shared__ float P[256][34];           // P[y][2*wm+{re,im}], padded stride 34
    __shared__ float ct[256], st[256];
    int t = threadIdx.x;
    ct[t] = ws[OFF_CT + t];
    st[t] = ws[OFF_ST + t];
    __syncthreads();

    const float* ub = u + (size_t)blockIdx.x * (H_ * W_);
    int yl = t & 31, h = t >> 5;           // h: 0..7 -> modes 2h, 2h+1
    int wm0 = 2 * h, wm1 = wm0 + 1;
    // r = e^{-i*2pi*wm/256} = (ct[(-wm)&255], st[(-wm)&255])
    float rr0 = ct[(256 - wm0) & 255], ri0 = st[(256 - wm0) & 255];
    float rr1 = ct[(256 - wm1) & 255], ri1 = st[(256 - wm1) & 255];

    for (int ch = 0; ch < 8; ++ch) {
        __syncthreads();
        const float4* src = (const float4*)(ub + ch * (32 * 256));
        #pragma unroll
        for (int k = 0; k < 8; ++k) {
            float4 vv = src[t + 256 * k];
            int fl = (t + 256 * k) << 2;
            int r = fl >> 8, c = fl & 255;
            ut[r][c]     = vv.x;
            ut[r][c + 1] = vv.y;
            ut[r][c + 2] = vv.z;
            ut[r][c + 3] = vv.w;
        }
        __syncthreads();
        float p0r = 0.f, p0i = 0.f, p1r = 0.f, p1i = 0.f;
        float t0r = 1.f, t0i = 0.f, t1r = 1.f, t1i = 0.f;
        #pragma unroll 4
        for (int x = 0; x < 256; ++x) {
            float uv = ut[yl][x];
            p0r = fmaf(uv, t0r, p0r);  p0i = fmaf(uv, t0i, p0i);
            p1r = fmaf(uv, t1r, p1r);  p1i = fmaf(uv, t1i, p1i);
            float n0r = t0r * rr0 - t0i * ri0;
            float n0i = t0r * ri0 + t0i * rr0;
            float n1r = t1r * rr1 - t1i * ri1;
            float n1i = t1r * ri1 + t1i * rr1;
            t0r = n0r; t0i = n0i; t1r = n1r; t1i = n1i;
        }
        int y = ch * 32 + yl;
        P[y][2 * wm0]     = p0r;  P[y][2 * wm0 + 1] = p0i;
        P[y][2 * wm1]     = p1r;  P[y][2 * wm1 + 1] = p1i;
    }
    __syncthreads();

    // stage 2: U[m][wm] = sum_y P[y][wm] * e^{-i*2pi*f(m)*y/256}
    int wm = t & 15, m1 = t >> 4;          // outputs m1 (f=m1) and m1+16 (f=m1-16)
    float q1r = ct[(256 - m1) & 255], q1i = st[(256 - m1) & 255]; // e^{-i th m1}
    float q2r = ct[(16 - m1) & 255],  q2i = st[(16 - m1) & 255];  // e^{-i th (m1-16)}
    float a1r = 0.f, a1i = 0.f, a2r = 0.f, a2i = 0.f;
    float w1r = 1.f, w1i = 0.f, w2r = 1.f, w2i = 0.f;
    #pragma unroll 4
    for (int y = 0; y < 256; ++y) {
        float pr = P[y][2 * wm], pi = P[y][2 * wm + 1];
        a1r = fmaf(pr, w1r, fmaf(-pi, w1i, a1r));
        a1i = fmaf(pr, w1i, fmaf( pi, w1r, a1i));
        a2r = fmaf(pr, w2r, fmaf(-pi, w2i, a2r));
        a2i = fmaf(pr, w2i, fmaf( pi, w2r, a2i));
        float n1r = w1r * q1r - w1i * q1i, n1i = w1r * q1i + w1i * q1r;
        float n2r = w2r * q2r - w2i * q2i, n2i = w2r * q2i + w2i * q2r;
        w1r = n1r; w1i = n1i; w2r = n2r; w2i = n2i;
    }
    float* Ub = U + (size_t)blockIdx.x * (NM_ * KW_ * 2);
    int o1 = (m1 * 16 + wm) * 2, o2 = ((m1 + 16) * 16 + wm) * 2;
    ((float2*)Ub)[o1 >> 1] = make_float2(a1r, a1i);
    ((float2*)Ub)[o2 >> 1] = make_float2(a2r, a2i);
}

// per-mode channel GEMM: one block per (m,wm)
__global__ __launch_bounds__(256) void k_cgemm(float* __restrict__ ws) {
    __shared__ float Ul[1024 * 2];        // [b*64+c] complex
    int mw = blockIdx.x;
    int t = threadIdx.x;
    const float2* Ug = (const float2*)(ws + OFF_U);
    #pragma unroll
    for (int k = 0; k < 4; ++k) {
        int bc = t + 256 * k;
        float2 uv = Ug[(size_t)bc * (NM_ * KW_) + mw];
        Ul[bc * 2]     = uv.x;
        Ul[bc * 2 + 1] = uv.y;
    }
    __syncthreads();
    int o = t & 63, bq = t >> 6;
    const float2* rp = (const float2*)(ws + OFF_RP + (size_t)mw * (CIN * COUT * 2));
    float ar[4] = {0.f, 0.f, 0.f, 0.f}, ai[4] = {0.f, 0.f, 0.f, 0.f};
    for (int c = 0; c < 64; ++c) {
        float2 R = rp[c * 64 + o];
        #pragma unroll
        for (int j = 0; j < 4; ++j) {
            int b = bq * 4 + j;
            float Ur = Ul[(b * 64 + c) * 2], Ui = Ul[(b * 64 + c) * 2 + 1];
            ar[j] = fmaf(Ur, R.x, fmaf(-Ui, R.y, ar[j]));
            ai[j] = fmaf(Ur, R.y, fmaf( Ui, R.x, ai[j]));
        }
    }
    float2* Vg = (float2*)(ws + OFF_V);
    #pragma unroll
    for (int j = 0; j < 4; ++j) {
        int b = bq * 4 + j;
        Vg[(size_t)(b * 64 + o) * (NM_ * KW_) + mw] = make_float2(ar[j], ai[j]);
    }
}

// inverse: one block per (b,o). Stage 4: inverse y-DFT; stage 5: x reconstruction.
__global__ __launch_bounds__(256) void k_inv(const float* __restrict__ ws,
                                             float* __restrict__ out) {
    __shared__ __align__(16) float Vl[16][68];      // [wm][2m+{re,im}]
    __shared__ __align__(16) float Tl[256][36];     // [y][0..15]=TR, [y][16..31]=TI
    __shared__ float ct[256], st[256];
    int t = threadIdx.x;
    ct[t] = ws[OFF_CT + t];
    st[t] = ws[OFF_ST + t];
    int bo = blockIdx.x;
    const float4* Vg = (const float4*)(ws + OFF_V + (size_t)bo * (NM_ * KW_ * 2));
    float4 vv = Vg[t];
    {
        float vals[4] = {vv.x, vv.y, vv.z, vv.w};
        int fj = 4 * t;
        #pragma unroll
        for (int jj = 0; jj < 4; ++jj) {
            int f = fj + jj, ci = f >> 1, comp = f & 1;
            int m = ci >> 4, wmv = ci & 15;
            Vl[wmv][2 * m + comp] = vals[jj];
        }
    }
    __syncthreads();

    // stage 4
    int wm4 = t & 15, yb = t >> 4;
    float vr[32], vi[32];
    #pragma unroll
    for (int m = 0; m < 32; ++m) { vr[m] = Vl[wm4][2 * m]; vi[m] = Vl[wm4][2 * m + 1]; }
    for (int rr = 0; rr < 16; ++rr) {
        int y = yb + 16 * rr;
        float cy = ct[y], sy = st[y];              // e^{+i*2pi*y/256}
        float tr = 1.f, ti = 0.f;
        float Tr = 0.f, Ti = 0.f;
        #pragma unroll
        for (int m = 0; m < 16; ++m) {             // f = m
            Tr = fmaf(vr[m], tr, fmaf(-vi[m], ti, Tr));
            Ti = fmaf(vr[m], ti, fmaf( vi[m], tr, Ti));
            float nr = tr * cy - ti * sy, ni = tr * sy + ti * cy;
            tr = nr; ti = ni;
        }
        int i16 = (-16 * y) & 255;                 // e^{+i*phi*(-16)}
        tr = ct[i16]; ti = st[i16];
        #pragma unroll
        for (int m = 16; m < 32; ++m) {            // f = m-32
            Tr = fmaf(vr[m], tr, fmaf(-vi[m], ti, Tr));
            Ti = fmaf(vr[m], ti, fmaf( vi[m], tr, Ti));
            float nr = tr * cy - ti * sy, ni = tr * sy + ti * cy;
            tr = nr; ti = ni;
        }
        Tl[y][wm4]      = Tr;
        Tl[y][16 + wm4] = Ti;
    }
    __syncthreads();

    // stage 5: out[y][x] = sum_wm TR*cos(2pi wm x/256) - TI*sin(...)
    int l = t & 63, wv = t >> 6;
    float c0[16], s0[16];
    #pragma unroll
    for (int wm = 0; wm < 16; ++wm) {
        int idx = (wm * l) & 255;
        c0[wm] = ct[idx]; s0[wm] = st[idx];
    }
    float* ob = out + (size_t)bo * (H_ * W_);
    for (int yi = 0; yi < 64; ++yi) {
        int y = wv * 64 + yi;
        float TR[16], TI[16];
        const float4* rowv = (const float4*)(&Tl[y][0]);
        #pragma unroll
        for (int q = 0; q < 4; ++q) {
            float4 a = rowv[q];
            TR[4 * q] = a.x; TR[4 * q + 1] = a.y; TR[4 * q + 2] = a.z; TR[4 * q + 3] = a.w;
            float4 b = rowv[q + 4];
            TI[4 * q] = b.x; TI[4 * q + 1] = b.y; TI[4 * q + 2] = b.z; TI[4 * q + 3] = b.w;
        }
        #pragma unroll
        for (int k = 0; k < 4; ++k) {
            float a = 0.f;
            #pragma unroll
            for (int wm = 0; wm < 16; ++wm) {
                int p = (k * wm) & 3;              // i^(k*wm): quarter-turn identity
                if (p == 0)      a += TR[wm] * c0[wm] - TI[wm] * s0[wm];
                else if (p == 1) a += -TR[wm] * s0[wm] - TI[wm] * c0[wm];
                else if (p == 2) a += -TR[wm] * c0[wm] + TI[wm] * s0[wm];
                else             a +=  TR[wm] * s0[wm] + TI[wm] * c0[wm];
            }
            ob[(size_t)y * 256 + 64 * k + l] = a;
        }
    }
}

extern "C" void kernel_launch(void* const* d_in, const int* in_sizes, int n_in,
                              void* d_out, int out_size, void* d_ws, size_t ws_size,
                              hipStream_t stream) {
    const float* u   = (const float*)d_in[0];
    const float* wpr = (const float*)d_in[1];
    const float* wpi = (const float*)d_in[2];
    const float* wnr = (const float*)d_in[3];
    const float* wni = (const float*)d_in[4];
    float* out = (float*)d_out;
    float* ws  = (float*)d_ws;

    hipLaunchKernelGGL(k_twiddle, dim3(1), dim3(256), 0, stream, ws);
    hipLaunchKernelGGL(k_repack, dim3(512), dim3(256), 0, stream, wpr, wpi, wnr, wni, ws);
    hipLaunchKernelGGL(k_fwd, dim3(1024), dim3(256), 0, stream, u, ws, ws + OFF_U);
    hipLaunchKernelGGL(k_cgemm, dim3(512), dim3(256), 0, stream, ws);
    hipLaunchKernelGGL(k_inv, dim3(1024), dim3(256), 0, stream, ws, out);
}

// Round 3
// 239.239 us; speedup vs baseline: 1.5694x; 1.5694x over previous
//
#include <hip/hip_runtime.h>

// SpectralConv2d: B=16, C_in=C_out=64, H=W=256, k=16.
// Retained modes: rows {0..15, 240..255} x cols {0..15} -> direct sparse DFTs.
//
// Pipeline (fp32):
//  k_twiddle : cos/sin(2*pi*t/256) tables -> ws
//  k_repack  : R'[c][o][m][wm] = (Wre + i Wim) * (wm==0?1:2)/65536   (coalesced)
//  k_fwd1    : x-DFT (quarter-turn grouped), P[b][c][y][wm] -> d_out (scratch)
//  k_fwd2    : y-DFT onto 32 row modes -> U[mw][b*64+c] (ws)
//  k_cgemm   : per (m,wm): V[b][o] = sum_c U[b][c]*R'[c][o]  (complex)
//  k_inv     : inverse y-DFT (4 quarters/rotation) + x reconstruction -> out

#define B_    16
#define H_    256
#define W_    256

// ws float offsets (total 6,291,968 floats = 25.17 MB)
#define OFF_CT 0
#define OFF_ST 256
#define OFF_RP 512
#define RP_SZ  (4096*512*2)                  // 4,194,304
#define OFF_U  (OFF_RP + RP_SZ)              // 4,194,816
#define U_SZ   (512*1024*2)                  // 1,048,576
#define OFF_V  (OFF_U + U_SZ)                // 5,243,392

typedef const __attribute__((address_space(1))) void g_void;
typedef __attribute__((address_space(3))) void l_void;

__device__ __forceinline__ void load_lds16(const float* g, float* l) {
    __builtin_amdgcn_global_load_lds((g_void*)g, (l_void*)l, 16, 0, 0);
}

__global__ void k_twiddle(float* __restrict__ ws) {
    int t = threadIdx.x;
    double a = 2.0 * 3.14159265358979323846 * (double)t / 256.0;
    ws[OFF_CT + t] = (float)cos(a);
    ws[OFF_ST + t] = (float)sin(a);
}

// grid 4096 = (c*64+o); fully coalesced read and write.
__global__ __launch_bounds__(256) void k_repack(const float* __restrict__ wpr,
                                                const float* __restrict__ wpi,
                                                const float* __restrict__ wnr,
                                                const float* __restrict__ wni,
                                                float* __restrict__ ws) {
    int co = blockIdx.x, t = threadIdx.x;      // t = i*16 + wm
    int wm = t & 15;
    float norm = (wm == 0 ? 1.f : 2.f) * (1.f / 65536.f);
    size_t src = (size_t)co * 256 + t;
    float2* rp = (float2*)(ws + OFF_RP) + (size_t)co * 512;
    rp[t]       = make_float2(wpr[src] * norm, wpi[src] * norm);   // m = i
    rp[t + 256] = make_float2(wnr[src] * norm, wni[src] * norm);   // m = i+16
}

// x-DFT. grid 8192 = (bc, chunk); block 256 = (yl 0..31) x (h 0..7, modes 2h,2h+1).
// x = j + 64k; twiddle(x) = twiddle(j)*(-i)^(wm*k); j runs j0..j0+63 (no wrap issues).
__global__ __launch_bounds__(256) void k_fwd1(const float* __restrict__ u,
                                              const float* __restrict__ ws,
                                              float* __restrict__ P) {
    __shared__ __align__(16) float ut[32][256];
    __shared__ float ct[256], st[256];
    int t = threadIdx.x;
    int bc = blockIdx.x >> 3, ch = blockIdx.x & 7;
    ct[t] = ws[OFF_CT + t];
    st[t] = ws[OFF_ST + t];
    const float* ub = u + (size_t)bc * 65536 + ch * 8192;
    int lane = t & 63, w = t >> 6;
    #pragma unroll
    for (int k = 0; k < 8; ++k) {
        int row = w * 8 + k;
        load_lds16(ub + row * 256 + lane * 4, &ut[row][0]);
    }
    asm volatile("s_waitcnt vmcnt(0)" ::: "memory");
    __syncthreads();

    int yl = t & 31, h = t >> 5;
    int wm0 = 2 * h, wm1 = wm0 + 1;
    int j0 = 2 * yl;                                   // bank-stagger start
    float t0r = ct[(wm0 * j0) & 255], t0i = -st[(wm0 * j0) & 255];
    float t1r = ct[(wm1 * j0) & 255], t1i = -st[(wm1 * j0) & 255];
    float r0r = ct[wm0], r0i = -st[wm0];
    float r1r = ct[wm1], r1i = -st[wm1];
    float bs  = (h & 1) ? -1.f : 1.f;                  // (-i)^(2h*k) = (-1)^(hk)
    float dsg = (h & 1) ? 1.f : -1.f;                  // g1 = c -/+ i d
    float p0r = 0.f, p0i = 0.f, p1r = 0.f, p1i = 0.f;
    const float* row = &ut[yl][0];
    #pragma unroll 8
    for (int s = 0; s < 64; ++s) {
        int j = j0 + s;                                // <= 125
        float u0 = row[j], u1 = row[j + 64], u2 = row[j + 128];
        float u3 = row[(j + 192) & 255];
        float a = u0 + u2, b = u1 + u3, c = u0 - u2, d = u1 - u3;
        float g0 = fmaf(bs, b, a);
        float g1r = c, g1i = dsg * d;
        p0r = fmaf(g0, t0r, p0r);
        p0i = fmaf(g0, t0i, p0i);
        p1r = fmaf(g1r, t1r, fmaf(-g1i, t1i, p1r));
        p1i = fmaf(g1r, t1i, fmaf( g1i, t1r, p1i));
        float n0r = t0r * r0r - t0i * r0i, n0i = t0r * r0i + t0i * r0r;
        float n1r = t1r * r1r - t1i * r1i, n1i = t1r * r1i + t1i * r1r;
        t0r = n0r; t0i = n0i; t1r = n1r; t1i = n1i;
    }
    int y = ch * 32 + yl;
    ((float4*)P)[((size_t)bc * 256 + y) * 8 + h] = make_float4(p0r, p0i, p1r, p1i);
}

// y-DFT. grid 1024 = bc. y = yy + 64k quarter-turn; md = m1&3 wave-uniform via remap.
__global__ __launch_bounds__(256) void k_fwd2(const float* __restrict__ P,
                                              float* __restrict__ ws) {
    __shared__ float Pl[256][36];
    __shared__ float ct[256], st[256];
    int t = threadIdx.x, bc = blockIdx.x;
    ct[t] = ws[OFF_CT + t];
    st[t] = ws[OFF_ST + t];
    const float4* Pg = (const float4*)(P + (size_t)bc * 8192);
    #pragma unroll
    for (int k = 0; k < 8; ++k) {
        int f4 = t + 256 * k;
        int y = f4 >> 3, q = f4 & 7;
        *(float4*)&Pl[y][q * 4] = Pg[f4];
    }
    __syncthreads();

    int wm = t & 15;
    int v  = t >> 4;
    int m1 = ((v & 3) << 2) | (v >> 2);               // md = m1&3 uniform per wave
    float r1r = ct[m1], r1i = -st[m1];                // e^{-2pi i m1/256}
    int m2i = (16 - m1) & 255;
    float r2r = ct[m2i], r2i = st[m2i];               // e^{-2pi i (m1-16)/256}
    float t1r = 1.f, t1i = 0.f, t2r = 1.f, t2i = 0.f;
    float U1r = 0.f, U1i = 0.f, U2r = 0.f, U2i = 0.f;
    int md = m1 & 3;
    #pragma unroll 4
    for (int yy = 0; yy < 64; ++yy) {
        float2 P0 = *(float2*)&Pl[yy][2 * wm];
        float2 P1 = *(float2*)&Pl[yy + 64][2 * wm];
        float2 P2 = *(float2*)&Pl[yy + 128][2 * wm];
        float2 P3 = *(float2*)&Pl[yy + 192][2 * wm];
        float ar = P0.x + P2.x, ai = P0.y + P2.y;
        float br = P1.x + P3.x, bi = P1.y + P3.y;
        float cr = P0.x - P2.x, ci = P0.y - P2.y;
        float dr = P1.x - P3.x, di = P1.y - P3.y;
        float gr, gi;
        if (md == 0)      { gr = ar + br; gi = ai + bi; }
        else if (md == 1) { gr = cr + di; gi = ci - dr; }   // g = c - i d
        else if (md == 2) { gr = ar - br; gi = ai - bi; }
        else              { gr = cr - di; gi = ci + dr; }   // g = c + i d
        U1r = fmaf(gr, t1r, fmaf(-gi, t1i, U1r));
        U1i = fmaf(gr, t1i, fmaf( gi, t1r, U1i));
        U2r = fmaf(gr, t2r, fmaf(-gi, t2i, U2r));
        U2i = fmaf(gr, t2i, fmaf( gi, t2r, U2i));
        float n1r = t1r * r1r - t1i * r1i, n1i = t1r * r1i + t1i * r1r;
        float n2r = t2r * r2r - t2i * r2i, n2i = t2r * r2i + t2i * r2r;
        t1r = n1r; t1i = n1i; t2r = n2r; t2i = n2i;
    }
    float2* U = (float2*)(ws + OFF_U);
    U[(size_t)(m1 * 16 + wm) * 1024 + bc]        = make_float2(U1r, U1i);
    U[(size_t)((m1 + 16) * 16 + wm) * 1024 + bc] = make_float2(U2r, U2i);
}

// per-mode channel GEMM: grid 512 = mw
__global__ __launch_bounds__(256) void k_cgemm(float* __restrict__ ws) {
    __shared__ float2 Ul[1024];
    int mw = blockIdx.x, t = threadIdx.x;
    const float2* Ug = (const float2*)(ws + OFF_U) + (size_t)mw * 1024;
    #pragma unroll
    for (int k = 0; k < 4; ++k) Ul[t + 256 * k] = Ug[t + 256 * k];
    __syncthreads();
    int o = t & 63, bq = t >> 6;
    const float2* rp = (const float2*)(ws + OFF_RP);
    float ar[4] = {0.f, 0.f, 0.f, 0.f}, ai[4] = {0.f, 0.f, 0.f, 0.f};
    #pragma unroll 4
    for (int c = 0; c < 64; ++c) {
        float2 R = rp[(size_t)(c * 64 + o) * 512 + mw];
        #pragma unroll
        for (int j = 0; j < 4; ++j) {
            float2 Uv = Ul[(bq * 4 + j) * 64 + c];     // wave-uniform -> broadcast
            ar[j] = fmaf(Uv.x, R.x, fmaf(-Uv.y, R.y, ar[j]));
            ai[j] = fmaf(Uv.x, R.y, fmaf( Uv.y, R.x, ai[j]));
        }
    }
    float2* Vg = (float2*)(ws + OFF_V);
    #pragma unroll
    for (int j = 0; j < 4; ++j)
        Vg[(size_t)((bq * 4 + j) * 64 + o) * 512 + mw] = make_float2(ar[j], ai[j]);
}

// inverse. grid 4096 = (bo, q); block covers y in {q*16+yb + 64g}.
__global__ __launch_bounds__(256) void k_inv(const float* __restrict__ ws,
                                             float* __restrict__ out) {
    __shared__ float Vl[16][68];
    __shared__ float Tl[4][16][36];
    __shared__ float ct[256], st[256];
    int t = threadIdx.x;
    int bo = blockIdx.x >> 2, q = blockIdx.x & 3;
    ct[t] = ws[OFF_CT + t];
    st[t] = ws[OFF_ST + t];
    {
        // V[bo] has 512 complex entries (32 m x 16 wm): load BOTH halves.
        const float2* Vg = (const float2*)(ws + OFF_V) + (size_t)bo * 512;
        float2 v0 = Vg[t];
        float2 v1 = Vg[t + 256];
        int m = t >> 4, wmv = t & 15;
        Vl[wmv][2 * m]            = v0.x;  Vl[wmv][2 * m + 1]            = v0.y;
        Vl[wmv][2 * (m + 16)]     = v1.x;  Vl[wmv][2 * (m + 16) + 1]     = v1.y;
    }
    __syncthreads();

    // stage 4: T[y0+64g] = sum_m V[m] e^{+2pi i f y0/256} * i^(f g)
    int wm4 = t & 15, yb = t >> 4;
    int y0 = q * 16 + yb;
    float vr[32], vi[32];
    #pragma unroll
    for (int m = 0; m < 32; ++m) { vr[m] = Vl[wm4][2 * m]; vi[m] = Vl[wm4][2 * m + 1]; }
    float cy = ct[y0], sy = st[y0];
    float T0r=0,T0i=0,T1r=0,T1i=0,T2r=0,T2i=0,T3r=0,T3i=0;
    float tr = 1.f, ti = 0.f;
    #pragma unroll
    for (int m = 0; m < 32; ++m) {
        if (m == 16) {
            int i16 = (4096 - 16 * y0) & 255;          // e^{-2pi i 16 y0/256}
            tr = ct[i16]; ti = st[i16];
        }
        float hr = vr[m] * tr - vi[m] * ti;
        float hi = vr[m] * ti + vi[m] * tr;
        const int md = m & 3;
        T0r += hr; T0i += hi;
        if (md == 0)      { T1r += hr; T1i += hi; T2r += hr; T2i += hi; T3r += hr; T3i += hi; }
        else if (md == 1) { T1r -= hi; T1i += hr; T2r -= hr; T2i -= hi; T3r += hi; T3i -= hr; }
        else if (md == 2) { T1r -= hr; T1i -= hi; T2r += hr; T2i += hi; T3r -= hr; T3i -= hi; }
        else              { T1r += hi; T1i -= hr; T2r -= hr; T2i -= hi; T3r -= hi; T3i += hr; }
        float nr = tr * cy - ti * sy, ni = tr * sy + ti * cy;
        tr = nr; ti = ni;
    }
    Tl[0][yb][wm4] = T0r; Tl[0][yb][16 + wm4] = T0i;
    Tl[1][yb][wm4] = T1r; Tl[1][yb][16 + wm4] = T1i;
    Tl[2][yb][wm4] = T2r; Tl[2][yb][16 + wm4] = T2i;
    Tl[3][yb][wm4] = T3r; Tl[3][yb][16 + wm4] = T3i;
    __syncthreads();

    // stage 5: out[y][64k+l] = sum_wm Re{(TR+iTI) e^{+i th wm(l+64k)}}
    int l = t & 63, wv = t >> 6;
    float c0[16], s0[16];
    #pragma unroll
    for (int wm = 0; wm < 16; ++wm) {
        int idx = (wm * l) & 255;
        c0[wm] = ct[idx]; s0[wm] = st[idx];
    }
    float* ob = out + (size_t)bo * 65536;
    for (int yi = 0; yi < 16; ++yi) {
        int y = wv * 64 + q * 16 + yi;
        float TR[16], TI[16];
        const float4* rowv = (const float4*)&Tl[wv][yi][0];
        #pragma unroll
        for (int qq = 0; qq < 4; ++qq) {
            float4 a = rowv[qq];
            TR[4*qq]=a.x; TR[4*qq+1]=a.y; TR[4*qq+2]=a.z; TR[4*qq+3]=a.w;
            float4 b = rowv[qq + 4];
            TI[4*qq]=b.x; TI[4*qq+1]=b.y; TI[4*qq+2]=b.z; TI[4*qq+3]=b.w;
        }
        #pragma unroll
        for (int k = 0; k < 4; ++k) {
            float a = 0.f;
            #pragma unroll
            for (int wm = 0; wm < 16; ++wm) {
                int p = (k * wm) & 3;
                if (p == 0)      a +=  TR[wm] * c0[wm] - TI[wm] * s0[wm];
                else if (p == 1) a += -TR[wm] * s0[wm] - TI[wm] * c0[wm];
                else if (p == 2) a += -TR[wm] * c0[wm] + TI[wm] * s0[wm];
                else             a +=  TR[wm] * s0[wm] + TI[wm] * c0[wm];
            }
            ob[(size_t)y * 256 + 64 * k + l] = a;
        }
    }
}

extern "C" void kernel_launch(void* const* d_in, const int* in_sizes, int n_in,
                              void* d_out, int out_size, void* d_ws, size_t ws_size,
                              hipStream_t stream) {
    const float* u   = (const float*)d_in[0];
    const float* wpr = (const float*)d_in[1];
    const float* wpi = (const float*)d_in[2];
    const float* wnr = (const float*)d_in[3];
    const float* wni = (const float*)d_in[4];
    float* out = (float*)d_out;
    float* ws  = (float*)d_ws;
    float* P   = (float*)d_out;            // 33.5 MB scratch in d_out (overwritten by k_inv)

    hipLaunchKernelGGL(k_twiddle, dim3(1),    dim3(256), 0, stream, ws);
    hipLaunchKernelGGL(k_repack,  dim3(4096), dim3(256), 0, stream, wpr, wpi, wnr, wni, ws);
    hipLaunchKernelGGL(k_fwd1,    dim3(8192), dim3(256), 0, stream, u, ws, P);
    hipLaunchKernelGGL(k_fwd2,    dim3(1024), dim3(256), 0, stream, P, ws);
    hipLaunchKernelGGL(k_cgemm,   dim3(512),  dim3(256), 0, stream, ws);
    hipLaunchKernelGGL(k_inv,     dim3(4096), dim3(256), 0, stream, ws, out);
}